// Round 10
// baseline (70.653 us; speedup 1.0000x reference)
//
#include <hip/hip_runtime.h>

#define N_NODES 50000
#define N_EDGES 100000
#define NUM_RELS 200
#define DIM 64
#define CAP 512
#define TILES 8

typedef __attribute__((ext_vector_type(8))) short bf16x8;
typedef __attribute__((ext_vector_type(8))) unsigned short u16x8;
typedef __attribute__((ext_vector_type(4))) float f32x4;

// ---- workspace layout ----
// int32 region:
#define OFF_LAST 0
#define OFF_CUR  50000
#define OFF_BN   50200
#define OFF_BS   152600          // 50200 + 200*512
// byte offsets (16B aligned):
#define HB_OFF   1020032u        // bf16 h: 50000*64 ushorts = 6.4 MB
#define WT_OFF   7420032u        // bf16 W^T (K-major): 201*64*64 ushorts

__device__ __forceinline__ unsigned short f2bf(float x) {
    union { float f; unsigned u; } v; v.f = x;
    unsigned r = v.u + 0x7FFFu + ((v.u >> 16) & 1u);   // RNE
    return (unsigned short)(r >> 16);
}

// ---------- K1: edge_max + W transpose/convert + h convert (init via memsets) ----------
#define K1_EDGE 391              // ceil(100000/256)
#define K1_WT   201              // 200 rels + wself at idx 200
#define K1_HC   391              // 32 floats per thread

__global__ __launch_bounds__(256) void prep_kernel(
    const float* __restrict__ h, const float* __restrict__ weight,
    const float* __restrict__ wself, const int* __restrict__ edges,
    int* __restrict__ ws, unsigned short* __restrict__ hb,
    unsigned short* __restrict__ wt)
{
    __shared__ float Wl[DIM * DIM];
    int b = blockIdx.x, t = threadIdx.x;

    if (b < K1_EDGE) {
        int e = b * 256 + t;
        if (e < N_EDGES) atomicMax(&ws[OFF_LAST + edges[e * 3 + 2]], e);
        return;
    }
    if (b < K1_EDGE + K1_WT) {
        int rel = b - K1_EDGE;
        const float* src = (rel < NUM_RELS) ? (weight + (size_t)rel * DIM * DIM) : wself;
#pragma unroll
        for (int j = 0; j < 16; ++j) Wl[t + j * 256] = src[t + j * 256];
        __syncthreads();
        int cc = t >> 2, q = t & 3;          // out-col, k-quarter
        unsigned short tmp[16];
#pragma unroll
        for (int kk = 0; kk < 16; ++kk)
            tmp[kk] = f2bf(Wl[(q * 16 + kk) * DIM + cc]);
        unsigned short* dst = wt + (size_t)rel * DIM * DIM + cc * DIM + q * 16;
        *(u16x8*)dst       = *(const u16x8*)&tmp[0];
        *(u16x8*)(dst + 8) = *(const u16x8*)&tmp[8];
        return;
    }
    {
        long off = (long)(b - K1_EDGE - K1_WT) * 8192 + (long)t * 32;
        if (off < (long)N_NODES * DIM) {
#pragma unroll
            for (int half = 0; half < 2; ++half) {
                const float4* src = (const float4*)(h + off + half * 16);
                unsigned short tmp[16];
#pragma unroll
                for (int j = 0; j < 4; ++j) {
                    float4 v = src[j];
                    tmp[j*4+0]=f2bf(v.x); tmp[j*4+1]=f2bf(v.y);
                    tmp[j*4+2]=f2bf(v.z); tmp[j*4+3]=f2bf(v.w);
                }
                *(u16x8*)(hb + off + half * 16)     = *(const u16x8*)&tmp[0];
                *(u16x8*)(hb + off + half * 16 + 8) = *(const u16x8*)&tmp[8];
            }
        }
    }
}

// ---------- K2: bucket + LDS-free self GEMM ----------
#define BK_BLKS 196              // ceil(50000/256)
#define NODE_TILES 782           // ceil(50000/64)

__global__ __launch_bounds__(256) void bucket_self_kernel(
    const int* __restrict__ edges, const unsigned short* __restrict__ hb,
    const unsigned short* __restrict__ wt, int* __restrict__ ws,
    float* __restrict__ out)
{
    int t = threadIdx.x;

    if (blockIdx.x < BK_BLKS) {
        int n = blockIdx.x * 256 + t;
        if (n < N_NODES) {
            int li = ws[OFF_LAST + n];
            if (li >= 0) {
                int r = edges[li * 3 + 1];
                int s = edges[li * 3 + 0];
                int pos = atomicAdd(&ws[OFF_CUR + r], 1);
                if (pos < CAP) {
                    ws[OFF_BN + r * CAP + pos] = n;
                    ws[OFF_BS + r * CAP + pos] = s;
                }
            }
        }
        return;
    }

    int base = (blockIdx.x - BK_BLKS) * 64;
    int l = t & 63;
    int w = __builtin_amdgcn_readfirstlane(t >> 6);   // 16-row strip
    int r16 = l & 15, kb = l >> 4;

    int arow = base + w * 16 + r16;
    if (arow >= N_NODES) arow = N_NODES - 1;          // OOB lanes feed only OOB C rows
    const unsigned short* ap = hb + (size_t)arow * DIM + kb * 8;
    bf16x8 a0 = *reinterpret_cast<const bf16x8*>(ap);
    bf16x8 a1 = *reinterpret_cast<const bf16x8*>(ap + 32);

    const unsigned short* wts = wt + (size_t)NUM_RELS * DIM * DIM;

    int nn[4]; bool vv[4];
#pragma unroll
    for (int r = 0; r < 4; ++r) {
        nn[r] = base + w * 16 + kb * 4 + r;           // C row = (l>>4)*4 + r
        vv[r] = nn[r] < N_NODES;
    }

#pragma unroll
    for (int n4 = 0; n4 < 4; ++n4) {
        const unsigned short* bp = wts + (n4 * 16 + r16) * DIM + kb * 8;
        bf16x8 b0 = *reinterpret_cast<const bf16x8*>(bp);
        bf16x8 b1 = *reinterpret_cast<const bf16x8*>(bp + 32);
        f32x4 acc = {0.f, 0.f, 0.f, 0.f};
        acc = __builtin_amdgcn_mfma_f32_16x16x32_bf16(a0, b0, acc, 0, 0, 0);
        acc = __builtin_amdgcn_mfma_f32_16x16x32_bf16(a1, b1, acc, 0, 0, 0);
#pragma unroll
        for (int r = 0; r < 4; ++r)
            if (vv[r]) out[(size_t)nn[r] * DIM + n4 * 16 + r16] = acc[r];
    }
}

// ---------- K3: LDS-free msg GEMM: out[n] += h[src] @ W[rel] ----------
__global__ __launch_bounds__(256) void msg_kernel(
    const unsigned short* __restrict__ hb, const unsigned short* __restrict__ wt,
    const int* __restrict__ ws, float* __restrict__ out)
{
    int rel = blockIdx.x >> 3;
    int tile = blockIdx.x & 7;
    int c = ws[OFF_CUR + rel];
    if (c > CAP) c = CAP;
    int start = tile * 64;
    if (start >= c) return;

    int t = threadIdx.x;
    int l = t & 63;
    int w = __builtin_amdgcn_readfirstlane(t >> 6);
    int r16 = l & 15, kb = l >> 4;
    const int* bn = ws + OFF_BN + rel * CAP;
    const int* bs = ws + OFF_BS + rel * CAP;

    int pa = start + w * 16 + r16;
    if (pa >= c) pa = c - 1;                          // OOB lanes feed only OOB C rows
    int s = bs[pa];
    const unsigned short* ap = hb + (size_t)s * DIM + kb * 8;
    bf16x8 a0 = *reinterpret_cast<const bf16x8*>(ap);
    bf16x8 a1 = *reinterpret_cast<const bf16x8*>(ap + 32);

    const unsigned short* wr = wt + (size_t)rel * DIM * DIM;

    int nn[4]; bool vv[4];
#pragma unroll
    for (int r = 0; r < 4; ++r) {
        int p = start + w * 16 + kb * 4 + r;
        vv[r] = p < c;
        nn[r] = bn[vv[r] ? p : 0];
    }

#pragma unroll
    for (int n4 = 0; n4 < 4; ++n4) {
        const unsigned short* bp = wr + (n4 * 16 + r16) * DIM + kb * 8;
        bf16x8 b0 = *reinterpret_cast<const bf16x8*>(bp);
        bf16x8 b1 = *reinterpret_cast<const bf16x8*>(bp + 32);
        f32x4 acc = {0.f, 0.f, 0.f, 0.f};
        acc = __builtin_amdgcn_mfma_f32_16x16x32_bf16(a0, b0, acc, 0, 0, 0);
        acc = __builtin_amdgcn_mfma_f32_16x16x32_bf16(a1, b1, acc, 0, 0, 0);
#pragma unroll
        for (int r = 0; r < 4; ++r)
            if (vv[r]) out[(size_t)nn[r] * DIM + n4 * 16 + r16] += acc[r];
    }
}

extern "C" void kernel_launch(void* const* d_in, const int* in_sizes, int n_in,
                              void* d_out, int out_size, void* d_ws, size_t ws_size,
                              hipStream_t stream) {
    const float* h      = (const float*)d_in[0];
    const int*   edges  = (const int*)d_in[1];
    const float* weight = (const float*)d_in[2];
    const float* wself  = (const float*)d_in[3];
    float* out = (float*)d_out;
    int* wsi = (int*)d_ws;
    unsigned short* hb = (unsigned short*)((char*)d_ws + HB_OFF);
    unsigned short* wt = (unsigned short*)((char*)d_ws + WT_OFF);

    hipMemsetAsync((char*)d_ws + (size_t)OFF_LAST * 4, 0xFF, (size_t)N_NODES * 4, stream);  // last = -1
    hipMemsetAsync((char*)d_ws + (size_t)OFF_CUR * 4, 0, (size_t)NUM_RELS * 4, stream);     // cur = 0

    prep_kernel<<<K1_EDGE + K1_WT + K1_HC, 256, 0, stream>>>(h, weight, wself, edges, wsi, hb, wt);
    bucket_self_kernel<<<BK_BLKS + NODE_TILES, 256, 0, stream>>>(edges, hb, wt, wsi, out);
    msg_kernel<<<NUM_RELS * TILES, 256, 0, stream>>>(hb, wt, wsi, out);
}